// Round 9
// baseline (106.918 us; speedup 1.0000x reference)
//
#include <hip/hip_runtime.h>
#include <hip/hip_bf16.h>

// ConvEncoder: emb gather (padding_idx=0) + WIN=5 im2col + Linear(640->128) + exact GELU
// dtypes: x int32, emb/W/b float32, OUTPUT float32.
// Round 9: two-kernel plan.
//  K1: stream-convert gathered embeddings -> Abf (bf16, 32768x128) and W -> Wbf
//      (bf16, 128x640) into d_ws, plus one zero row. Kills the x->emb dependent
//      chain and all cvt VALU work in the GEMM kernel.
//  K2: GEMM C = A_im2col x W^T + GELU. sEmb staged LINEARLY from Abf (1 barrier),
//      B-fragments read per-wave straight from L2-hot Wbf (no sW, no K-loop
//      barriers -> waves free-run; the R7/R8 barrier-phase serialization is gone).

#define EMB   128
#define WIN   5
#define OUTC  128
#define SEQ   2048
#define KTOT  640
#define MTILE 64
#define NTILE 64

#define EMB_STRIDE 136   // elems; 272-B rows: 16-row-strided b128 reads spread banks (free)

// d_ws layout (bytes)
#define ABF_OFF   0
#define ABF_BYTES (32768ull * 128 * 2)          // 8,388,608
#define WBF_OFF   ABF_BYTES                      // 8,388,608
#define WBF_BYTES (128ull * 640 * 2)             // 163,840
#define ZROW_OFF  (WBF_OFF + WBF_BYTES)          // 8,552,448
#define NTASK_A   (32768 * 16)                   // 16-B chunks of Abf
#define NTASK_W   (10240)                        // 16-B chunks of Wbf
#define NTASK_Z   (16)
#define NTASK_TOT (NTASK_A + NTASK_W + NTASK_Z)

typedef __bf16  bf16x8 __attribute__((ext_vector_type(8)));
typedef float   f32x4  __attribute__((ext_vector_type(4)));
typedef ushort  u16x8  __attribute__((ext_vector_type(8)));

__device__ inline ushort f2bf(float f) {
    __bf16 h = (__bf16)f;  // RNE
    return __builtin_bit_cast(ushort, h);
}

__device__ inline u16x8 cvt8v(float4 v0, float4 v1) {
    u16x8 o;
    o[0] = f2bf(v0.x); o[1] = f2bf(v0.y); o[2] = f2bf(v0.z); o[3] = f2bf(v0.w);
    o[4] = f2bf(v1.x); o[5] = f2bf(v1.y); o[6] = f2bf(v1.z); o[7] = f2bf(v1.w);
    return o;
}

// ---------------- K1: gather + convert ----------------
__global__ __launch_bounds__(256) void prep_kernel(
    const int* __restrict__ x,       // (32768,)
    const float* __restrict__ emb,   // (50257, 128)
    const float* __restrict__ W,     // (128, 640)
    ushort* __restrict__ ws)         // bf16 workspace
{
    int t = blockIdx.x * 256 + threadIdx.x;
    for (; t < NTASK_TOT; t += gridDim.x * 256) {
        if (t < NTASK_A) {
            const int row = t >> 4, c = t & 15;
            const int tok = x[row];
            const float* p = emb + (size_t)tok * EMB + c * 8;
            *(u16x8*)(ws + (size_t)row * EMB + c * 8) =
                cvt8v(*(const float4*)p, *(const float4*)(p + 4));
        } else if (t < NTASK_A + NTASK_W) {
            const int i = t - NTASK_A;
            const float* p = W + (size_t)i * 8;
            *(u16x8*)(ws + WBF_OFF / 2 + (size_t)i * 8) =
                cvt8v(*(const float4*)p, *(const float4*)(p + 4));
        } else {
            const int i = t - NTASK_A - NTASK_W;
            *(u16x8*)(ws + ZROW_OFF / 2 + (size_t)i * 8) = (u16x8){0,0,0,0,0,0,0,0};
        }
    }
}

// ---------------- K2: GEMM + bias + exact GELU ----------------
__global__ __launch_bounds__(256, 4) void conv_encoder_kernel(
    const ushort* __restrict__ ws,   // Abf / Wbf / zrow
    const float* __restrict__ bias,  // (128,)
    float* __restrict__ out)         // (32768, 128)
{
    __shared__ ushort sEmb[(MTILE + WIN - 1) * EMB_STRIDE]; // 68 rows, 18.5 KB

    const int tid = threadIdx.x;
    const int mi  = blockIdx.x;            // 0..511
    const int n0  = blockIdx.y * NTILE;    // N half
    const int m0  = mi * MTILE;
    const int bb  = m0 >> 11;
    const int s0  = m0 & (SEQ - 1);

    const ushort* Abf  = ws;
    const ushort* Wbf  = ws + WBF_OFF / 2;
    const ushort* zrow = ws + ZROW_OFF / 2;

    // ---- Stage A rows linearly (bf16, no cvt, no token dependency) ----
    for (int idx = tid; idx < (MTILE + WIN - 1) * 16; idx += 256) {
        const int r = idx >> 4, c = idx & 15;
        const int s = s0 - 2 + r;
        const ushort* src = (s >= 0 && s < SEQ)
            ? Abf + ((size_t)(bb * SEQ + s)) * EMB + c * 8
            : zrow + c * 8;
        *(u16x8*)(&sEmb[r * EMB_STRIDE + c * 8]) = *(const u16x8*)src;
    }
    __syncthreads();   // the ONLY barrier

    const int lane = tid & 63;
    const int wv   = tid >> 6;
    const int qr   = (wv >> 1) * 32;
    const int qc   = (wv & 1) * 32;
    const int lr   = lane & 15;
    const int lk8  = (lane >> 4) * 8;

    f32x4 acc[2][2];
    #pragma unroll
    for (int i = 0; i < 2; ++i)
        #pragma unroll
        for (int j = 0; j < 2; ++j)
            acc[i][j] = (f32x4){0.f, 0.f, 0.f, 0.f};

    // Per-lane W base: row n0+qc+j*16+lr, k offset lk8
    const ushort* wbase0 = Wbf + (size_t)(n0 + qc + lr) * KTOT + lk8;
    const ushort* wbase1 = wbase0 + 16 * KTOT;

    // ---- K loop: no barriers; B-frags from global (L2-hot), A-frags from LDS ----
    for (int win = 0; win < WIN; ++win) {
        #pragma unroll
        for (int kc = 0; kc < 4; ++kc) {
            const int e  = kc * 32 + lk8;
            const int ko = win * EMB + kc * 32;
            bf16x8 afr[2], bfr[2];
            bfr[0] = *(const bf16x8*)(wbase0 + ko);
            bfr[1] = *(const bf16x8*)(wbase1 + ko);
            #pragma unroll
            for (int i = 0; i < 2; ++i)
                afr[i] = *(const bf16x8*)(&sEmb[(qr + i * 16 + lr + win) * EMB_STRIDE + e]);
            #pragma unroll
            for (int i = 0; i < 2; ++i)
                #pragma unroll
                for (int j = 0; j < 2; ++j)
                    acc[i][j] = __builtin_amdgcn_mfma_f32_16x16x32_bf16(afr[i], bfr[j], acc[i][j], 0, 0, 0);
        }
    }

    // ---- Epilogue: bias + exact GELU + fp32 store ----
    float bj[2];
    #pragma unroll
    for (int j = 0; j < 2; ++j)
        bj[j] = bias[n0 + qc + j * 16 + lr];

    const int rbase = (lane >> 4) * 4;
    #pragma unroll
    for (int i = 0; i < 2; ++i) {
        #pragma unroll
        for (int j = 0; j < 2; ++j) {
            const int col = n0 + qc + j * 16 + lr;
            #pragma unroll
            for (int r = 0; r < 4; ++r) {
                const int row = m0 + qr + i * 16 + rbase + r;
                const float y = acc[i][j][r] + bj[j];
                const float g = 0.5f * y * (1.0f + erff(y * 0.70710678118654752f));
                out[(size_t)row * OUTC + col] = g;
            }
        }
    }
}

extern "C" void kernel_launch(void* const* d_in, const int* in_sizes, int n_in,
                              void* d_out, int out_size, void* d_ws, size_t ws_size,
                              hipStream_t stream) {
    (void)in_sizes; (void)n_in; (void)ws_size; (void)out_size;
    const int* x        = (const int*)d_in[0];
    const float* emb    = (const float*)d_in[1];
    const float* Wm     = (const float*)d_in[2];
    const float* bias   = (const float*)d_in[3];
    float* out          = (float*)d_out;
    ushort* ws          = (ushort*)d_ws;

    hipLaunchKernelGGL(prep_kernel, dim3(2048), dim3(256), 0, stream, x, emb, Wm, ws);
    hipLaunchKernelGGL(conv_encoder_kernel, dim3(32768 / MTILE, OUTC / NTILE), dim3(256),
                       0, stream, ws, bias, out);
}

// Round 10
// 103.154 us; speedup vs baseline: 1.0365x; 1.0365x over previous
//
#include <hip/hip_runtime.h>
#include <hip/hip_bf16.h>

// ConvEncoder: emb gather (padding_idx=0) + WIN=5 im2col + Linear(640->128) + exact GELU
// dtypes: x int32, emb/W/b float32, OUTPUT float32.
// Round 10: single kernel, ONE barrier total.
//  - sEmb (18.5 KB) staged with inline gather+cvt, then one __syncthreads.
//  - K-loop is barrier-free: A-frags from LDS, B-frags per-lane from fp32 W in
//    L2 (16 rows x 128 B per wave-load, fully coalesced), cvt to bf16 in-loop.
//  - Wave tile 64x32 (acc[4][2]); block = 4 waves = 64x128 tile; grid 512.

#define EMB   128
#define WIN   5
#define OUTC  128
#define SEQ   2048
#define KTOT  640
#define MTILE 64

#define EMB_STRIDE 136   // elems; 272-B rows; 16-row-strided b128 reads are 2-way (free)

typedef __bf16  bf16x8 __attribute__((ext_vector_type(8)));
typedef float   f32x4  __attribute__((ext_vector_type(4)));
typedef ushort  u16x8  __attribute__((ext_vector_type(8)));

__device__ inline ushort f2bf(float f) {
    __bf16 h = (__bf16)f;  // RNE
    return __builtin_bit_cast(ushort, h);
}

__device__ inline u16x8 cvt8v(float4 v0, float4 v1) {
    u16x8 o;
    o[0] = f2bf(v0.x); o[1] = f2bf(v0.y); o[2] = f2bf(v0.z); o[3] = f2bf(v0.w);
    o[4] = f2bf(v1.x); o[5] = f2bf(v1.y); o[6] = f2bf(v1.z); o[7] = f2bf(v1.w);
    return o;
}

__global__ __launch_bounds__(256, 4) void conv_encoder_kernel(
    const int* __restrict__ x,                 // (16, 2048)
    const float* __restrict__ emb,             // (50257, 128), row 0 zero
    const float* __restrict__ W,               // (128, 640)
    const float* __restrict__ bias,            // (128,)
    float* __restrict__ out)                   // (32768, 128)
{
    __shared__ ushort sEmb[(MTILE + WIN - 1) * EMB_STRIDE]; // 68 rows, 18.5 KB

    const int tid = threadIdx.x;
    const int m0  = blockIdx.x * MTILE;
    const int bb  = m0 >> 11;
    const int s0  = m0 & (SEQ - 1);

    // ---- Stage embeddings (68 rows x 128 elems), gather + cvt f32->bf16 ----
    {
        const int xbase = bb * SEQ;
        for (int idx = tid; idx < (MTILE + WIN - 1) * 16; idx += 256) {
            const int r = idx >> 4, c = idx & 15;
            const int s = s0 - 2 + r;
            const int tok = (s >= 0 && s < SEQ) ? x[xbase + s] : 0;
            const float* p = emb + (size_t)tok * EMB + c * 8;
            *(u16x8*)(&sEmb[r * EMB_STRIDE + c * 8]) =
                cvt8v(*(const float4*)p, *(const float4*)(p + 4));
        }
    }
    __syncthreads();   // the ONLY barrier

    const int lane = tid & 63;
    const int wv   = tid >> 6;         // wave col group: cols wv*32 .. wv*32+31
    const int lr   = lane & 15;
    const int lk8  = (lane >> 4) * 8;

    f32x4 acc[4][2];
    #pragma unroll
    for (int i = 0; i < 4; ++i)
        #pragma unroll
        for (int j = 0; j < 2; ++j)
            acc[i][j] = (f32x4){0.f, 0.f, 0.f, 0.f};

    // Per-lane W row bases (fp32): rows wv*32 + j*16 + lr
    const float* w0 = W + (size_t)(wv * 32 + lr) * KTOT + lk8;
    const float* w1 = w0 + 16 * KTOT;

    // ---- K loop: barrier-free. A from LDS, B from L2-hot fp32 W + inline cvt ----
    #pragma unroll
    for (int win = 0; win < WIN; ++win) {
        #pragma unroll
        for (int kc = 0; kc < 4; ++kc) {
            const int e  = kc * 32 + lk8;          // col within sEmb row
            const int ko = win * EMB + kc * 32;    // k offset within W row
            bf16x8 bfr[2], afr[4];
            bfr[0] = __builtin_bit_cast(bf16x8,
                cvt8v(*(const float4*)(w0 + ko), *(const float4*)(w0 + ko + 4)));
            bfr[1] = __builtin_bit_cast(bf16x8,
                cvt8v(*(const float4*)(w1 + ko), *(const float4*)(w1 + ko + 4)));
            #pragma unroll
            for (int i = 0; i < 4; ++i)
                afr[i] = *(const bf16x8*)(&sEmb[(i * 16 + lr + win) * EMB_STRIDE + e]);
            #pragma unroll
            for (int i = 0; i < 4; ++i)
                #pragma unroll
                for (int j = 0; j < 2; ++j)
                    acc[i][j] = __builtin_amdgcn_mfma_f32_16x16x32_bf16(afr[i], bfr[j], acc[i][j], 0, 0, 0);
        }
    }

    // ---- Epilogue: bias + exact GELU + fp32 store ----
    float bj[2];
    #pragma unroll
    for (int j = 0; j < 2; ++j)
        bj[j] = bias[wv * 32 + j * 16 + lr];

    const int rbase = (lane >> 4) * 4;
    #pragma unroll
    for (int i = 0; i < 4; ++i) {
        #pragma unroll
        for (int j = 0; j < 2; ++j) {
            const int col = wv * 32 + j * 16 + lr;
            #pragma unroll
            for (int r = 0; r < 4; ++r) {
                const int row = m0 + i * 16 + rbase + r;
                const float y = acc[i][j][r] + bj[j];
                const float g = 0.5f * y * (1.0f + erff(y * 0.70710678118654752f));
                out[(size_t)row * OUTC + col] = g;
            }
        }
    }
}

extern "C" void kernel_launch(void* const* d_in, const int* in_sizes, int n_in,
                              void* d_out, int out_size, void* d_ws, size_t ws_size,
                              hipStream_t stream) {
    (void)in_sizes; (void)n_in; (void)d_ws; (void)ws_size; (void)out_size;
    const int* x        = (const int*)d_in[0];
    const float* emb    = (const float*)d_in[1];
    const float* Wm     = (const float*)d_in[2];
    const float* bias   = (const float*)d_in[3];
    float* out          = (float*)d_out;

    dim3 grid(32768 / MTILE);   // 512 blocks, 2/CU
    dim3 block(256);
    hipLaunchKernelGGL(conv_encoder_kernel, grid, block, 0, stream, x, emb, Wm, bias, out);
}